// Round 11
// baseline (71.134 us; speedup 1.0000x reference)
//
#include <hip/hip_runtime.h>

typedef unsigned int u32;
typedef __fp16 h2v __attribute__((ext_vector_type(2)));
typedef __fp16 h4 __attribute__((ext_vector_type(4)));
typedef float f32x16 __attribute__((ext_vector_type(16)));

#define NB 256
#define NNODE 256
#define FF 128
#define DD 8
#define HDIM 32
#define NROWS (NB*NNODE)

__device__ __forceinline__ float dot2(h2v a, h2v b, float c) {
  return __builtin_amdgcn_fdot2(a, b, c, false);
}
__device__ __forceinline__ h2v bch2(u32 u) { return __builtin_bit_cast(h2v, u); }
__device__ __forceinline__ h4 bch4(uint2 u) { return __builtin_bit_cast(h4, u); }
__device__ __forceinline__ u32 bcu(h2v v) { return __builtin_bit_cast(u32, v); }
__device__ __forceinline__ f32x16 fzero() {
  f32x16 z;
  #pragma unroll
  for (int r = 0; r < 16; ++r) z[r] = 0.f;
  return z;
}
__device__ __forceinline__ f32x16 mfma8(h4 a, h4 b, f32x16 c) {
  return __builtin_amdgcn_mfma_f32_32x32x8f16(a, b, c, 0, 0, 0);
}

// -------- prep: W-pack + bias + edge scatter (mask pre-zeroed via memset) -------
__global__ __launch_bounds__(256) void prep_kernel(
    const float* __restrict__ Wq, const float* __restrict__ bq,
    const float* __restrict__ Wk, const float* __restrict__ bk,
    const float* __restrict__ Wv, const float* __restrict__ bv,
    const int* __restrict__ eidx, int E,
    u32* __restrict__ mask, u32* __restrict__ WtH, float* __restrict__ bias)
{
  int g = blockIdx.x * 256 + threadIdx.x;
  if (g < 96 * 64) {                 // WtH[c][kp]: pack W[2kp][c], W[2kp+1][c]
    int c = g >> 6, f = (g & 63) * 2;
    const float* W = (c < 32) ? Wq : ((c < 64) ? Wk : Wv);
    int cc = c & 31;
    WtH[g] = bcu(__builtin_amdgcn_cvt_pkrtz(W[f*HDIM + cc], W[(f+1)*HDIM + cc]));
  }
  if (g < 96) {
    const float* bb = (g < 32) ? bq : ((g < 64) ? bk : bv);
    bias[g] = bb[g & 31];
  }
  if (g < E) {
    int r = eidx[g], c = eidx[E + g];
    atomicOr(&mask[r*8 + (c >> 5)], 1u << (c & 31));
  }
}

// -------- qkv: 1 wave per block, 32 rows; W-frags from global (L1-resident) ----
__global__ __launch_bounds__(64) void qkv_kernel(
    const float* __restrict__ x, const u32* __restrict__ WtH,
    const float* __restrict__ bias,
    __fp16* __restrict__ qh, __fp16* __restrict__ kh, __fp16* __restrict__ vh)
{
  int lane = threadIdx.x, l31 = lane & 31, hi = lane >> 5;
  int row0 = blockIdx.x * 32;
  const float* xr = x + ((size_t)row0 + l31) * FF + 4 * hi;

  f32x16 A[3];
  #pragma unroll
  for (int ct = 0; ct < 3; ++ct) {
    float bb = bias[ct*32 + l31];
    #pragma unroll
    for (int r = 0; r < 16; ++r) A[ct][r] = bb;
  }
  #pragma unroll
  for (int ks = 0; ks < 16; ++ks) {
    float4 xf = *(const float4*)(xr + ks * 8);
    h2v xl = __builtin_amdgcn_cvt_pkrtz(xf.x, xf.y);
    h2v xh = __builtin_amdgcn_cvt_pkrtz(xf.z, xf.w);
    h4 xfrag = __builtin_shufflevector(xl, xh, 0, 1, 2, 3);
    #pragma unroll
    for (int ct = 0; ct < 3; ++ct) {
      h4 wf = bch4(*(const uint2*)(WtH + (size_t)(ct*32 + l31)*64 + ks*4 + 2*hi));
      A[ct] = mfma8(xfrag, wf, A[ct]);   // lane=col(hd), regs=node-rows
    }
  }
  #pragma unroll
  for (int ct = 0; ct < 3; ++ct) {
    __fp16* dst = (ct == 0) ? qh : ((ct == 1) ? kh : vh);
    #pragma unroll
    for (int r = 0; r < 16; ++r) {
      int row = row0 + (r & 3) + 8*(r >> 2) + 4*hi;
      dst[(size_t)row * HDIM + l31] = (__fp16)A[ct][r];
    }
  }
}

// -------- attn+proj: block = (batch, q-half); 4 waves; 1 stage barrier ---------
__global__ __launch_bounds__(256, 3) void attn_kernel(
    const __fp16* __restrict__ qh, const __fp16* __restrict__ kh,
    const __fp16* __restrict__ vh, const u32* __restrict__ mask,
    const float* __restrict__ Wo, const float* __restrict__ bo,
    float* __restrict__ out)
{
  __shared__ u32 kSu[NNODE * 18];      // K rows, stride 18 u32 (36 f16)
  __shared__ __fp16 vtS[32 * 260];     // V^T all heads [hd][node], stride 260
  __shared__ __fp16 oS[128 * 36];      // attn out rows, stride 36
  __shared__ u32 woPk[128];            // Wo^T packed pairs [d][p]
  __shared__ float boS[8];

  int t = threadIdx.x, lane = t & 63, w = t >> 6;   // w = q-tile 0..3
  int l31 = lane & 31, hi = lane >> 5;
  int b = blockIdx.x >> 1, half = blockIdx.x & 1;

  // stage K (coalesced u32 copy)
  const u32* khU = (const u32*)kh + (size_t)b * NNODE * 16;
  #pragma unroll
  for (int i = 0; i < 16; ++i) {
    int id = t + i * 256;
    kSu[(id >> 4) * 18 + (id & 15)] = khU[id];
  }
  // stage V^T: FULL row (32 f16 = 4 uint4) -> column scatter, all 32 hd rows
  {
    const uint4* vrow = (const uint4*)(vh + ((size_t)b * NNODE + t) * HDIM);
    uint4 v0 = vrow[0], v1 = vrow[1], v2 = vrow[2], v3 = vrow[3];
    u32 vv[16] = { v0.x, v0.y, v0.z, v0.w, v1.x, v1.y, v1.z, v1.w,
                   v2.x, v2.y, v2.z, v2.w, v3.x, v3.y, v3.z, v3.w };
    #pragma unroll
    for (int i = 0; i < 16; ++i) {
      h2v pp = bch2(vv[i]);
      vtS[(2*i  )*260 + t] = pp.x;
      vtS[(2*i+1)*260 + t] = pp.y;
    }
  }
  if (t < 128) {                       // woPk[d*16+p] = pack(Wo[2p][d], Wo[2p+1][d])
    int d = t >> 4, p = t & 15;
    woPk[t] = bcu(__builtin_amdgcn_cvt_pkrtz(Wo[(2*p)*DD + d], Wo[(2*p+1)*DD + d]));
  }
  if (t < 8) boS[t] = bo[t];

  // wave-private: masks + Q frags (global, pre-barrier)
  int qnode = half*128 + w*32 + l31;
  uint4 m0 = *(const uint4*)(mask + qnode*8);
  uint4 m1 = *(const uint4*)(mask + qnode*8 + 4);
  u32 mw8[8] = { m0.x, m0.y, m0.z, m0.w, m1.x, m1.y, m1.z, m1.w };
  #pragma unroll
  for (int i = 0; i < 8; ++i) mw8[i] = hi ? (mw8[i] >> 4) : mw8[i];
  const u32* qU = (const u32*)qh + ((size_t)b * NNODE + qnode) * 16;
  h4 Qf[4];
  #pragma unroll
  for (int h = 0; h < 4; ++h)
    Qf[h] = bch4(*(const uint2*)(qU + 4*h + 2*hi));

  __syncthreads();

  const float sc2 = 0.51006977f;       // (1/sqrt(8)) * log2(e)
  const h2v one2 = bch2(0x3C003C00u);  // (1.0h, 1.0h)
  #pragma unroll
  for (int hp = 0; hp < 2; ++hp) {
    int h0 = 2*hp, h1 = 2*hp + 1;
    f32x16 accO0 = fzero(), accO1 = fzero();
    float lp0 = 0.f, lp1 = 0.f;
    #pragma unroll
    for (int kt = 0; kt < 8; ++kt) {
      h4 Kf0 = bch4(*(const uint2*)&kSu[(kt*32 + l31)*18 + 4*h0 + 2*hi]);
      h4 Kf1 = bch4(*(const uint2*)&kSu[(kt*32 + l31)*18 + 4*h1 + 2*hi]);
      f32x16 T0 = mfma8(Kf0, Qf[h0], fzero());   // T[kr][q=l31]
      f32x16 T1 = mfma8(Kf1, Qf[h1], fzero());
      u32 mwh = mw8[kt];
      float mbv[16];
      #pragma unroll
      for (int r = 0; r < 16; ++r) {             // select on constants, shared x2
        int bp = (r & 3) + 8*(r >> 2);
        mbv[r] = ((mwh >> bp) & 1u) ? -8.0f : -1e30f;
      }
      u32 pw0[8], pw1[8];
      #pragma unroll
      for (int j = 0; j < 8; ++j) {
        float p00 = __builtin_amdgcn_exp2f(__builtin_fmaf(T0[2*j],   sc2, mbv[2*j]));
        float p01 = __builtin_amdgcn_exp2f(__builtin_fmaf(T0[2*j+1], sc2, mbv[2*j+1]));
        float p10 = __builtin_amdgcn_exp2f(__builtin_fmaf(T1[2*j],   sc2, mbv[2*j]));
        float p11 = __builtin_amdgcn_exp2f(__builtin_fmaf(T1[2*j+1], sc2, mbv[2*j+1]));
        pw0[j] = bcu(__builtin_amdgcn_cvt_pkrtz(p00, p01));
        pw1[j] = bcu(__builtin_amdgcn_cvt_pkrtz(p10, p11));
        lp0 = dot2(bch2(pw0[j]), one2, lp0);     // l-sum on packed pairs
        lp1 = dot2(bch2(pw1[j]), one2, lp1);
      }
      #pragma unroll
      for (int kk = 0; kk < 4; ++kk) {
        h4 va = bch4(*(const uint2*)&vtS[l31*260 + kt*32 + kk*8 + 4*hi]);
        accO0 = mfma8(va, bch4(make_uint2(pw0[2*kk], pw0[2*kk+1])), accO0);
        accO1 = mfma8(va, bch4(make_uint2(pw1[2*kk], pw1[2*kk+1])), accO1);
      }
    }
    float lq0 = lp0 + __shfl_xor(lp0, 32);
    float lq1 = lp1 + __shfl_xor(lp1, 32);
    float inv0 = 1.0f / lq0, inv1 = 1.0f / lq1;
    h2v a0 = __builtin_amdgcn_cvt_pkrtz(accO0[4*h0]*inv0,   accO0[4*h0+1]*inv0);
    h2v a1 = __builtin_amdgcn_cvt_pkrtz(accO0[4*h0+2]*inv0, accO0[4*h0+3]*inv0);
    *(uint2*)&oS[(w*32 + l31)*36 + 8*h0 + 4*hi] = make_uint2(bcu(a0), bcu(a1));
    h2v c0 = __builtin_amdgcn_cvt_pkrtz(accO1[4*h1]*inv1,   accO1[4*h1+1]*inv1);
    h2v c1 = __builtin_amdgcn_cvt_pkrtz(accO1[4*h1+2]*inv1, accO1[4*h1+3]*inv1);
    *(uint2*)&oS[(w*32 + l31)*36 + 8*h1 + 4*hi] = make_uint2(bcu(c0), bcu(c1));
  }
  __syncthreads();

  // ---- proj: thread = (row, d-half); out = oS @ Wo + bo ----
  int row = t >> 1, d4 = (t & 1) * 4;
  float r4[4] = { boS[d4], boS[d4+1], boS[d4+2], boS[d4+3] };
  #pragma unroll
  for (int p = 0; p < 16; ++p) {
    h2v o2 = bch2(*(const u32*)&oS[row*36 + 2*p]);
    #pragma unroll
    for (int d = 0; d < 4; ++d)
      r4[d] = dot2(o2, bch2(woPk[(d4 + d)*16 + p]), r4[d]);
  }
  float4 o = { r4[0], r4[1], r4[2], r4[3] };
  *(float4*)(out + ((size_t)b * NNODE + half*128 + row) * DD + d4) = o;
}

extern "C" void kernel_launch(void* const* d_in, const int* in_sizes, int n_in,
                              void* d_out, int out_size, void* d_ws, size_t ws_size,
                              hipStream_t stream)
{
  const float* x  = (const float*)d_in[0];
  const int*   ei = (const int*)d_in[1];
  const float* Wq = (const float*)d_in[2];
  const float* bq = (const float*)d_in[3];
  const float* Wk = (const float*)d_in[4];
  const float* bk = (const float*)d_in[5];
  const float* Wv = (const float*)d_in[6];
  const float* bv = (const float*)d_in[7];
  const float* Wo = (const float*)d_in[8];
  const float* bo = (const float*)d_in[9];
  int E = in_sizes[1] / 2;

  char* ws = (char*)d_ws;
  u32*   mask = (u32*)(ws + 0);                 // 8 KB
  u32*   WtH  = (u32*)(ws + 8192);              // 24 KB
  float* bias = (float*)(ws + 32768);           // 384 B
  __fp16* qh  = (__fp16*)(ws + 65536);          // 4 MB each
  __fp16* kh  = qh + (size_t)NROWS * HDIM;
  __fp16* vh  = kh + (size_t)NROWS * HDIM;

  hipMemsetAsync(mask, 0, NNODE * 8 * sizeof(u32), stream);
  int prep_work = (96*64 > E) ? 96*64 : E;
  prep_kernel<<<(prep_work + 255)/256, 256, 0, stream>>>(
      Wq, bq, Wk, bk, Wv, bv, ei, E, mask, WtH, bias);
  qkv_kernel<<<NROWS / 32, 64, 0, stream>>>(x, WtH, bias, qh, kh, vh);
  attn_kernel<<<NB * 2, 256, 0, stream>>>(qh, kh, vh, mask, Wo, bo,
                                          (float*)d_out);
}

// Round 12
// 41.746 us; speedup vs baseline: 1.7040x; 1.7040x over previous
//
#include <hip/hip_runtime.h>

typedef unsigned int u32;
typedef __fp16 h2v __attribute__((ext_vector_type(2)));
typedef __fp16 h4 __attribute__((ext_vector_type(4)));
typedef float f32x16 __attribute__((ext_vector_type(16)));

#define NB 256
#define NNODE 256
#define FF 128
#define DD 8
#define HDIM 32

__device__ __forceinline__ float dot2(h2v a, h2v b, float c) {
  return __builtin_amdgcn_fdot2(a, b, c, false);
}
__device__ __forceinline__ h2v bch2(u32 u) { return __builtin_bit_cast(h2v, u); }
__device__ __forceinline__ h4 bch4(uint2 u) { return __builtin_bit_cast(h4, u); }
__device__ __forceinline__ u32 bcu(h2v v) { return __builtin_bit_cast(u32, v); }
__device__ __forceinline__ f32x16 fzero() {
  f32x16 z;
  #pragma unroll
  for (int r = 0; r < 16; ++r) z[r] = 0.f;
  return z;
}
__device__ __forceinline__ f32x16 mfma8(h4 a, h4 b, f32x16 c) {
  return __builtin_amdgcn_mfma_f32_32x32x8f16(a, b, c, 0, 0, 0);
}

// -------- prep_w: zero mask; WtH[c][kp] f16-packed W^T; bias f32; WoT packed ----
__global__ __launch_bounds__(256) void prep_w_kernel(
    const float* __restrict__ Wq, const float* __restrict__ bq,
    const float* __restrict__ Wk, const float* __restrict__ bk,
    const float* __restrict__ Wv, const float* __restrict__ bv,
    const float* __restrict__ Wo,
    u32* __restrict__ mask, u32* __restrict__ WtH, float* __restrict__ bias,
    u32* __restrict__ woT2)
{
  int g = blockIdx.x * 256 + threadIdx.x;
  if (g < 96 * 64) {                      // WtH[c][kp]: pack W[2kp][c],W[2kp+1][c]
    int c = g >> 6, f = (g & 63) * 2;
    const float* W = (c < 32) ? Wq : ((c < 64) ? Wk : Wv);
    int cc = c & 31;
    WtH[g] = bcu(__builtin_amdgcn_cvt_pkrtz(W[f*HDIM + cc], W[(f+1)*HDIM + cc]));
  }
  if (g < NNODE * 8) mask[g] = 0u;
  if (g < 96) {
    const float* bb = (g < 32) ? bq : ((g < 64) ? bk : bv);
    bias[g] = bb[g & 31];
  }
  if (g < 128) {                          // woT2[d][p] = pack Wo[2p][d],Wo[2p+1][d]
    int d = g >> 4, p = g & 15;
    woT2[g] = bcu(__builtin_amdgcn_cvt_pkrtz(Wo[(2*p)*DD + d], Wo[(2*p+1)*DD + d]));
  }
}

__global__ __launch_bounds__(256) void prep_e_kernel(
    const int* __restrict__ eidx, int E, u32* __restrict__ mask)
{
  int e = blockIdx.x * 256 + threadIdx.x;
  if (e < E) {
    int r = eidx[e], c = eidx[E + e];
    atomicOr(&mask[r*8 + (c >> 5)], 1u << (c & 31));
  }
}

// -------- fused: 2 blocks/batch (4 waves); merged-QKV -> 4-chain attn -> proj ---
__global__ __launch_bounds__(256, 2) void fused_kernel(
    const float* __restrict__ x, const u32* __restrict__ WtH,
    const float* __restrict__ bias, const u32* __restrict__ mask,
    const u32* __restrict__ woT2, const float* __restrict__ bo,
    float* __restrict__ out)
{
  __shared__ u32 wLds[96 * 66];        // 25.3 KB; stride 66 -> banks spread
  __shared__ __fp16 kS[NNODE * 36];    // 18 KB, stride 36 f16
  __shared__ __fp16 vt32[32 * 260];    // 16.3 KB, V^T all heads, stride 260
  __shared__ __fp16 oS[128 * 36];      // 9 KB, own q-rows
  __shared__ u32 woS[128];
  __shared__ float boS[8];

  int t = threadIdx.x, lane = t & 63, w = t >> 6;   // 4 waves
  int l31 = lane & 31, hi = lane >> 5;
  int b = blockIdx.x >> 1, half = blockIdx.x & 1;

  // stage W (coalesced global read, strided LDS write)
  for (int g = t; g < 96 * 64; g += 256)
    wLds[(g >> 6) * 66 + (g & 63)] = WtH[g];
  if (t < 128) woS[t] = woT2[t];
  if (t < 8) boS[t] = bo[t];

  // accumulator init
  f32x16 aq, ak0, av0, ak1, av1;
  #pragma unroll
  for (int r = 0; r < 16; ++r) aq[r] = bias[(r & 3) + 8*(r >> 2) + 4*hi];
  {
    float bk_ = bias[32 + l31], bv_ = bias[64 + l31];
    #pragma unroll
    for (int r = 0; r < 16; ++r) { ak0[r]=bk_; av0[r]=bv_; ak1[r]=bk_; av1[r]=bv_; }
  }

  // adjacency words for own q-row (issued early; overlaps W-stage latency)
  int node = half*128 + w*32 + l31;
  uint4 m0 = *(const uint4*)(mask + node * 8);
  uint4 m1 = *(const uint4*)(mask + node * 8 + 4);
  u32 mw8[8] = { m0.x, m0.y, m0.z, m0.w, m1.x, m1.y, m1.z, m1.w };
  #pragma unroll
  for (int i = 0; i < 8; ++i) mw8[i] = hi ? (mw8[i] >> 4) : mw8[i];

  __syncthreads();                     // wLds ready

  // ---- QKV: merged dual-tile loop; wave w -> tiles w and w+4 ----
  const float* xr0 = x + ((size_t)b * NNODE + w*32 + l31) * FF + 4 * hi;
  const float* xr1 = xr0 + (size_t)128 * FF;
  #pragma unroll
  for (int ks = 0; ks < 16; ++ks) {
    float4 xf0 = *(const float4*)(xr0 + ks * 8);
    float4 xf1 = *(const float4*)(xr1 + ks * 8);
    h2v a0 = __builtin_amdgcn_cvt_pkrtz(xf0.x, xf0.y);
    h2v b0 = __builtin_amdgcn_cvt_pkrtz(xf0.z, xf0.w);
    h4 f0 = __builtin_shufflevector(a0, b0, 0, 1, 2, 3);
    h2v a1 = __builtin_amdgcn_cvt_pkrtz(xf1.x, xf1.y);
    h2v b1 = __builtin_amdgcn_cvt_pkrtz(xf1.z, xf1.w);
    h4 f1 = __builtin_shufflevector(a1, b1, 0, 1, 2, 3);
    h4 wk = bch4(*(const uint2*)&wLds[(32 + l31)*66 + ks*4 + 2*hi]);
    h4 wv = bch4(*(const uint2*)&wLds[(64 + l31)*66 + ks*4 + 2*hi]);
    h4 wq = bch4(*(const uint2*)&wLds[l31*66 + ks*4 + 2*hi]);
    ak0 = mfma8(f0, wk, ak0);          // k: lane=hd-col, regs=node-rows
    ak1 = mfma8(f1, wk, ak1);
    av0 = mfma8(f0, wv, av0);
    av1 = mfma8(f1, wv, av1);
    aq  = mfma8(wq, half ? f1 : f0, aq);   // q^T of own tile: lane=node, regs=hd
  }
  #pragma unroll
  for (int r = 0; r < 16; ++r) {
    int rc = (r & 3) + 8*(r >> 2) + 4*hi;
    int n0 = w*32 + rc, n1 = n0 + 128;
    kS[n0 * 36 + l31] = (__fp16)ak0[r];
    kS[n1 * 36 + l31] = (__fp16)ak1[r];
    vt32[l31 * 260 + n0] = (__fp16)av0[r];
    vt32[l31 * 260 + n1] = (__fp16)av1[r];
  }
  // Q B-frags straight from aq regs
  h4 Qf[4];
  #pragma unroll
  for (int h = 0; h < 4; ++h) {
    h2v qa = __builtin_amdgcn_cvt_pkrtz(aq[4*h],     aq[4*h + 1]);
    h2v qb = __builtin_amdgcn_cvt_pkrtz(aq[4*h + 2], aq[4*h + 3]);
    Qf[h] = __builtin_shufflevector(qa, qb, 0, 1, 2, 3);
  }
  __syncthreads();

  // ---- attention: 4 head-chains in flight ----
  const float sc2 = 0.51006977f;       // (1/sqrt(8)) * log2(e)
  const h2v one2 = bch2(0x3C003C00u);  // (1.0h, 1.0h)
  f32x16 accO[4] = { fzero(), fzero(), fzero(), fzero() };
  float lp[4] = { 0.f, 0.f, 0.f, 0.f };
  #pragma unroll
  for (int kt = 0; kt < 8; ++kt) {
    u32 mwh = mw8[kt];
    float mbv[16];
    #pragma unroll
    for (int r = 0; r < 16; ++r) {     // select on constants, shared across heads
      int bp = (r & 3) + 8*(r >> 2);
      mbv[r] = ((mwh >> bp) & 1u) ? -8.0f : -1e30f;
    }
    u32 pw[4][8];
    #pragma unroll
    for (int h = 0; h < 4; ++h) {
      h4 Kf = bch4(*(const uint2*)&kS[(kt*32 + l31)*36 + 8*h + 4*hi]);
      f32x16 T = mfma8(Kf, Qf[h], fzero());      // T[kr][q=l31]
      #pragma unroll
      for (int j = 0; j < 8; ++j) {
        float p0 = __builtin_amdgcn_exp2f(__builtin_fmaf(T[2*j],   sc2, mbv[2*j]));
        float p1 = __builtin_amdgcn_exp2f(__builtin_fmaf(T[2*j+1], sc2, mbv[2*j+1]));
        pw[h][j] = bcu(__builtin_amdgcn_cvt_pkrtz(p0, p1));
        lp[h] = dot2(bch2(pw[h][j]), one2, lp[h]);   // l-sum on packed pairs
      }
    }
    __builtin_amdgcn_s_setprio(1);
    #pragma unroll
    for (int kk = 0; kk < 4; ++kk) {
      h4 va = bch4(*(const uint2*)&vt32[l31*260 + kt*32 + kk*8 + 4*hi]);
      #pragma unroll
      for (int h = 0; h < 4; ++h)
        accO[h] = mfma8(va, bch4(make_uint2(pw[h][2*kk], pw[h][2*kk+1])), accO[h]);
    }
    __builtin_amdgcn_s_setprio(0);
  }
  // epilogue: head h output lives in accO[h] regs 4h..4h+3 (col q=l31)
  #pragma unroll
  for (int h = 0; h < 4; ++h) {
    float lq = lp[h] + __shfl_xor(lp[h], 32);
    float inv = 1.0f / lq;
    h2v o0 = __builtin_amdgcn_cvt_pkrtz(accO[h][4*h]*inv,   accO[h][4*h+1]*inv);
    h2v o1 = __builtin_amdgcn_cvt_pkrtz(accO[h][4*h+2]*inv, accO[h][4*h+3]*inv);
    *(uint2*)&oS[(w*32 + l31)*36 + 8*h + 4*hi] = make_uint2(bcu(o0), bcu(o1));
  }
  __syncthreads();

  // ---- proj: 2 threads per row; out = oS @ Wo + bo ----
  int pr = t >> 1, d4 = (t & 1) * 4;
  float r4[4] = { boS[d4], boS[d4+1], boS[d4+2], boS[d4+3] };
  #pragma unroll
  for (int p = 0; p < 16; ++p) {
    h2v o2 = bch2(*(const u32*)&oS[pr*36 + 2*p]);
    #pragma unroll
    for (int d = 0; d < 4; ++d)
      r4[d] = dot2(o2, bch2(woS[(d4 + d)*16 + p]), r4[d]);
  }
  float4 o = { r4[0], r4[1], r4[2], r4[3] };
  *(float4*)(out + ((size_t)b * NNODE + half*128 + pr) * DD + d4) = o;
}

extern "C" void kernel_launch(void* const* d_in, const int* in_sizes, int n_in,
                              void* d_out, int out_size, void* d_ws, size_t ws_size,
                              hipStream_t stream)
{
  const float* x  = (const float*)d_in[0];
  const int*   ei = (const int*)d_in[1];
  const float* Wq = (const float*)d_in[2];
  const float* bq = (const float*)d_in[3];
  const float* Wk = (const float*)d_in[4];
  const float* bk = (const float*)d_in[5];
  const float* Wv = (const float*)d_in[6];
  const float* bv = (const float*)d_in[7];
  const float* Wo = (const float*)d_in[8];
  const float* bo = (const float*)d_in[9];
  int E = in_sizes[1] / 2;

  char* ws = (char*)d_ws;
  u32*   mask = (u32*)(ws + 0);                 // 8 KB
  u32*   WtH  = (u32*)(ws + 8192);              // 24 KB: W^T[c][kp] f16-packed
  float* bias = (float*)(ws + 32768);           // 384 B
  u32*   woT2 = (u32*)(ws + 33280);             // 512 B

  prep_w_kernel<<<24, 256, 0, stream>>>(Wq, bq, Wk, bk, Wv, bv, Wo,
                                        mask, WtH, bias, woT2);
  prep_e_kernel<<<(E + 255) / 256, 256, 0, stream>>>(ei, E, mask);
  fused_kernel<<<NB * 2, 256, 0, stream>>>(x, WtH, bias, mask, woT2, bo,
                                           (float*)d_out);
}